// Round 8
// baseline (579.872 us; speedup 1.0000x reference)
//
#include <hip/hip_runtime.h>
#include <math.h>

typedef float floatx2 __attribute__((ext_vector_type(2)));

#define NODE_MASK 0x07FFFFFF

__device__ __forceinline__ float wave_sum(float v){
#pragma unroll
  for (int m = 1; m < 64; m <<= 1) v += __shfl_xor(v, m, 64);
  return v;
}

__device__ __forceinline__ unsigned short bf16_of(float a){
  unsigned ua = __float_as_uint(a);
  ua = (ua + 0x7FFFu + ((ua >> 16) & 1u)) >> 16;
  return (unsigned short)ua;
}
__device__ __forceinline__ unsigned pack_bf16(float a, float b){
  unsigned ua = __float_as_uint(a), ub = __float_as_uint(b);
  ua = (ua + 0x7FFFu + ((ua >> 16) & 1u)) >> 16;
  ub = (ub + 0x7FFFu + ((ub >> 16) & 1u)) >> 16;
  return ua | (ub << 16);
}
__device__ __forceinline__ float2 unpack_bf16(unsigned p){
  float2 r;
  r.x = __uint_as_float(p << 16);
  r.y = __uint_as_float(p & 0xFFFF0000u);
  return r;
}

// ---------------- CSR build (dst-major, self-loop first per node) ----------------
__global__ void k_deg_count(const int* __restrict__ dst, int* __restrict__ deg, int e){
  int i = blockIdx.x*blockDim.x + threadIdx.x;
  if (i < e) atomicAdd(&deg[dst[i]], 1);
}

// ---- parallel exclusive scan of (deg[i]+1) -> rowptr ----
__global__ void k_scan_a(const int* __restrict__ deg, int* __restrict__ rowptr,
                         int* __restrict__ bsum, int n){
  __shared__ int sm[256];
  int i = blockIdx.x*256 + threadIdx.x;
  int v = (i < n) ? (deg[i] + 1) : 0;   // +1 self loop
  sm[threadIdx.x] = v; __syncthreads();
#pragma unroll
  for (int off = 1; off < 256; off <<= 1){
    int t = (threadIdx.x >= off) ? sm[threadIdx.x - off] : 0;
    __syncthreads();
    sm[threadIdx.x] += t;
    __syncthreads();
  }
  if (i < n) rowptr[i] = sm[threadIdx.x] - v;   // exclusive within block
  if (threadIdx.x == 255) bsum[blockIdx.x] = sm[255];
}

__global__ void k_scan_b(int* __restrict__ bsum, int* __restrict__ rowptr, int nb, int n){
  __shared__ int sm[256];
  int t = threadIdx.x;
  int v = (t < nb) ? bsum[t] : 0;
  sm[t] = v; __syncthreads();
#pragma unroll
  for (int off = 1; off < 256; off <<= 1){
    int x = (t >= off) ? sm[t - off] : 0;
    __syncthreads();
    sm[t] += x;
    __syncthreads();
  }
  if (t < nb) bsum[t] = sm[t] - v;              // exclusive block offsets
  if (t == 255) rowptr[n] = sm[255];            // total
}

// fused: add block offset, write self-loop entry (with packed batch), init cursor, zero gc
__global__ void k_scan_c_selfloop(int* __restrict__ rowptr, const int* __restrict__ bsum,
                                  int* __restrict__ cursor, int* __restrict__ csr,
                                  const int* __restrict__ batch,
                                  float* __restrict__ gc, int n){
  int i = blockIdx.x*256 + threadIdx.x;
  if (i < n){
    int r = rowptr[i] + bsum[blockIdx.x];
    rowptr[i] = r;
    csr[r] = i | (batch[i] << 27);   // self loop entry, batch in top bits
    cursor[i] = r + 1;
  }
  if (blockIdx.x == 0){
    gc[threadIdx.x] = 0.f;
    gc[threadIdx.x + 256] = 0.f;
  }
}

// scatter src (+packed batch) into csr; record rank with a COALESCED write
__global__ void k_scatter(const int* __restrict__ src, const int* __restrict__ dst,
                          const int* __restrict__ batch,
                          int* __restrict__ cursor, int* __restrict__ csr,
                          int* __restrict__ epos, int e){
  int i = blockIdx.x*blockDim.x + threadIdx.x;
  if (i < e){
    int d = dst[i];
    int sv = src[i];
    int pos = atomicAdd(&cursor[d], 1);
    csr[pos] = sv | (batch[sv] << 27);
    epos[i] = pos - d - 1;        // rank in self-loop-free CSR (coalesced store)
  }
}

// ------- per-layer node transforms: xl(bf16), xr, residual(+bias); 8 nodes/wave -------
template<int K>
__global__ void k_node_transform(const float* __restrict__ h,
                                 const float* __restrict__ Wl, const float* __restrict__ bl,
                                 const float* __restrict__ Wr, const float* __restrict__ br,
                                 const float* __restrict__ Wres, const float* __restrict__ bias,
                                 unsigned short* __restrict__ xlh, float* __restrict__ xr,
                                 float* __restrict__ res, int n){
  int wq   = (blockIdx.x*blockDim.x + threadIdx.x) >> 6;
  int lane = threadIdx.x & 63;
  int n0 = wq * 8;
  if (n0 >= n) return;
  float hv[8];
#pragma unroll
  for (int j = 0; j < 8; ++j){
    int node = min(n0 + j, n - 1);
    hv[j] = (lane < K) ? h[(size_t)node*K + lane] : 0.f;
  }
  float aL[8], aR[8], aS[8];
  float blv = bl[lane], brv = br[lane], bsv = bias[lane];
#pragma unroll
  for (int j = 0; j < 8; ++j){ aL[j] = blv; aR[j] = brv; aS[j] = bsv; }
#pragma unroll 4
  for (int k = 0; k < K; ++k){
    float wl = Wl[k*64+lane], wr = Wr[k*64+lane], wsv = Wres[k*64+lane];
#pragma unroll
    for (int j = 0; j < 8; ++j){
      float hk = __shfl(hv[j], k, 64);
      aL[j] = fmaf(hk, wl,  aL[j]);
      aR[j] = fmaf(hk, wr,  aR[j]);
      aS[j] = fmaf(hk, wsv, aS[j]);
    }
  }
#pragma unroll
  for (int j = 0; j < 8; ++j){
    int node = n0 + j;
    if (node < n){
      size_t o = (size_t)node*64 + lane;
      xlh[o] = bf16_of(aL[j]);
      xr[o] = aR[j]; res[o] = aS[j];
    }
  }
}

// --- fused: edge softmax (online, 4 slots, prefetch-2, bf16 xl gathers) + LN + relu ---
__global__ void k_gat_edge(const unsigned* __restrict__ xl_u, const float* __restrict__ xr,
                           const float* __restrict__ att,
                           const float* __restrict__ lng, const float* __restrict__ lnb,
                           const int* __restrict__ rowptr, const int* __restrict__ csr,
                           float* __restrict__ hio /* in: residual, out: h_next */, int n){
  int node = (blockIdx.x*blockDim.x + threadIdx.x) >> 6;
  int lane = threadIdx.x & 63;
  if (node >= n) return;
  int sub = lane >> 4;          // edge slot (0..3)
  int l   = lane & 15;          // channels 4l .. 4l+3
  size_t base = (size_t)node*64 + 4*l;
  float4 xrv  = *(const float4*)&xr[base];
  float4 attv = *(const float4*)&att[4*l];
  int p0 = rowptr[node], p1 = rowptr[node+1];
  int deg = p1 - p0;            // >= 1 (self loop)
  int sreg = csr[p0 + min(lane, deg-1)];   // cache first 64 packed entries in regs
  int rounds = (deg + 3) >> 2;
  float m = -1e30f, dsum = 0.f;
  float a0=0.f, a1=0.f, a2=0.f, a3=0.f;
  // 2-deep prefetch pipeline
  int e0 = sub;
  bool v0 = e0 < deg;
  int s0 = __shfl(sreg, v0 ? e0 : 0, 64) & NODE_MASK;
  uint2 x0 = *(const uint2*)&xl_u[(size_t)s0*32 + 2*l];
  int e1 = 4 + sub;
  bool v1 = e1 < deg;
  uint2 x1 = x0;
  if (rounds > 1){
    int s1;
    if (e1 < 64) s1 = __shfl(sreg, v1 ? e1 : 0, 64);
    else         s1 = csr[p0 + (v1 ? e1 : 0)];
    s1 &= NODE_MASK;
    x1 = *(const uint2*)&xl_u[(size_t)s1*32 + 2*l];
  }
  for (int r = 0; r < rounds; ++r){
    int en = 4*(r+2) + sub;
    bool vn = en < deg;
    uint2 xn = x0;
    if (r + 2 < rounds){
      int sn;
      if (en < 64) sn = __shfl(sreg, vn ? en : 0, 64);
      else         sn = csr[p0 + (vn ? en : 0)];
      sn &= NODE_MASK;
      xn = *(const uint2*)&xl_u[(size_t)sn*32 + 2*l];
    }
    // compute current (x0, v0)
    float2 p01 = unpack_bf16(x0.x);
    float2 p23 = unpack_bf16(x0.y);
    float vx = p01.x + xrv.x, vy = p01.y + xrv.y;
    float vz = p23.x + xrv.z, vw = p23.y + xrv.w;
    vx = vx > 0.f ? vx : 0.2f*vx;  vy = vy > 0.f ? vy : 0.2f*vy;
    vz = vz > 0.f ? vz : 0.2f*vz;  vw = vw > 0.f ? vw : 0.2f*vw;
    float partial = fmaf(vx, attv.x, fmaf(vy, attv.y, fmaf(vz, attv.z, vw*attv.w)));
#pragma unroll
    for (int mm = 1; mm < 16; mm <<= 1) partial += __shfl_xor(partial, mm, 64);
    float logit = v0 ? partial : -3e30f;
    float nm = fmaxf(m, logit);
    float sc = __expf(m - nm);
    float w  = __expf(logit - nm);
    dsum = fmaf(dsum, sc, w);
    a0 = fmaf(a0, sc, w*p01.x);
    a1 = fmaf(a1, sc, w*p01.y);
    a2 = fmaf(a2, sc, w*p23.x);
    a3 = fmaf(a3, sc, w*p23.y);
    m = nm;
    x0 = x1; v0 = v1;
    x1 = xn; v1 = vn;
  }
  // merge the 4 sub-groups' online-softmax states (xor 16, then xor 32)
#pragma unroll
  for (int off = 16; off < 64; off <<= 1){
    float mo = __shfl_xor(m, off, 64);
    float M  = fmaxf(m, mo);
    float sc = __expf(m - M);
    dsum *= sc; a0 *= sc; a1 *= sc; a2 *= sc; a3 *= sc;
    m = M;
    dsum += __shfl_xor(dsum, off, 64);
    a0 += __shfl_xor(a0, off, 64);
    a1 += __shfl_xor(a1, off, 64);
    a2 += __shfl_xor(a2, off, 64);
    a3 += __shfl_xor(a3, off, 64);
  }
  float4 resv = *(const float4*)&hio[base];
  float inv = 1.f / dsum;
  float ox = fmaf(a0, inv, resv.x);
  float oy = fmaf(a1, inv, resv.y);
  float oz = fmaf(a2, inv, resv.z);
  float ow = fmaf(a3, inv, resv.w);
  // layernorm over 64 channels; each channel appears 4x across the wave
  float mean = wave_sum(ox + oy + oz + ow) * (1.f/256.f);
  float dx = ox - mean, dy = oy - mean, dz = oz - mean, dw = ow - mean;
  float var = wave_sum(fmaf(dx,dx, fmaf(dy,dy, fmaf(dz,dz, dw*dw)))) * (1.f/256.f);
  float rstd = rsqrtf(var + 1e-5f);
  if (sub == 0){
    float4 lg = *(const float4*)&lng[4*l];
    float4 lb = *(const float4*)&lnb[4*l];
    float4 out;
    out.x = fmaxf(fmaf(dx*rstd, lg.x, lb.x), 0.f);
    out.y = fmaxf(fmaf(dy*rstd, lg.y, lb.y), 0.f);
    out.z = fmaxf(fmaf(dz*rstd, lg.z, lb.z), 0.f);
    out.w = fmaxf(fmaf(dw*rstd, lg.w, lb.w), 0.f);
    *(float4*)&hio[base] = out;
  }
}

// ---------------- global add pool (batch is sorted) ----------------
__global__ void k_pool(const float* __restrict__ h, const int* __restrict__ batch,
                       float* __restrict__ gc, int n){
  int wid  = (blockIdx.x*blockDim.x + threadIdx.x) >> 6;
  int lane = threadIdx.x & 63;
  int n0 = wid*64;
  if (n0 >= n) return;
  int n1 = min(n0+64, n);
  int curg = batch[n0];
  float s = 0.f;
  for (int i = n0; i < n1; ++i){
    int g = batch[i];
    if (g != curg){ atomicAdd(&gc[curg*64+lane], s); s = 0.f; curg = g; }
    s += h[(size_t)i*64 + lane];
  }
  atomicAdd(&gc[curg*64+lane], s);
}

// ---------------- G[g] = gc[g] @ W1c + b1 ----------------
__global__ void k_graph_proj(const float* __restrict__ gc, const float* __restrict__ W1,
                             const float* __restrict__ b1, float* __restrict__ G){
  int g = threadIdx.x >> 7;       // 8 graphs x 128 cols = 1024 threads
  int j = threadIdx.x & 127;
  float a = b1[j];
#pragma unroll 8
  for (int k = 0; k < 64; ++k) a = fmaf(gc[g*64+k], W1[(128+k)*128 + j], a);
  G[g*128 + j] = a;
}

// ---- A = nr @ W1a (fp8 packed) ; B = nr @ W1b (bf16 packed); 8 nodes per wave ----
__global__ void k_node_proj(const float* __restrict__ nr, const float* __restrict__ W1,
                            unsigned short* __restrict__ Au16, unsigned* __restrict__ Bu, int n){
  int wq   = (blockIdx.x*blockDim.x + threadIdx.x) >> 6;
  int lane = threadIdx.x & 63;
  int n0 = wq * 8;
  if (n0 >= n) return;
  float hv[8];
#pragma unroll
  for (int j = 0; j < 8; ++j){
    int node = min(n0 + j, n - 1);
    hv[j] = nr[(size_t)node*64 + lane];
  }
  float a0[8], a1[8], b0[8], b1v[8];
#pragma unroll
  for (int j = 0; j < 8; ++j){ a0[j]=0.f; a1[j]=0.f; b0[j]=0.f; b1v[j]=0.f; }
#pragma unroll 4
  for (int k = 0; k < 64; ++k){
    float2 wa = *(const float2*)&W1[k*128 + 2*lane];
    float2 wb = *(const float2*)&W1[(64+k)*128 + 2*lane];
#pragma unroll
    for (int j = 0; j < 8; ++j){
      float hk = __shfl(hv[j], k, 64);
      a0[j]  = fmaf(hk, wa.x, a0[j]);
      a1[j]  = fmaf(hk, wa.y, a1[j]);
      b0[j]  = fmaf(hk, wb.x, b0[j]);
      b1v[j] = fmaf(hk, wb.y, b1v[j]);
    }
  }
#pragma unroll
  for (int j = 0; j < 8; ++j){
    int node = n0 + j;
    if (node < n){
      size_t o = (size_t)node*64 + lane;
      Au16[o] = (unsigned short)__builtin_amdgcn_cvt_pk_fp8_f32(a0[j], a1[j], 0, false);
      Bu[o] = pack_bf16(b0[j], b1v[j]);
    }
  }
}

// -- final per-edge MLP, dst-major: B[d] once, A[s] fp8-gathered (prefetch-2), tmp coalesced --
// wave per node; 4 edge slots x 16 lanes (8 channels per lane); batch packed in csr
__global__ void k_edge_out_csr(const uint2* __restrict__ Au2, const uint4* __restrict__ Bu4,
                               const float* __restrict__ G,
                               const int* __restrict__ rowptr, const int* __restrict__ csr,
                               const float* __restrict__ W2, const float* __restrict__ b2,
                               float* __restrict__ tmp, int n){
  int node = (blockIdx.x*blockDim.x + threadIdx.x) >> 6;
  int lane = threadIdx.x & 63;
  if (node >= n) return;
  int sub = lane >> 4;
  int l   = lane & 15;            // channels 8l .. 8l+7
  int p0 = rowptr[node];
  int deg2 = rowptr[node+1] - p0 - 1;      // excludes self loop
  if (deg2 <= 0) return;
  int sreg = csr[p0 + 1 + min(lane, deg2-1)];   // cache first 64 packed entries
  uint4 b = Bu4[(size_t)node*16 + l];      // B[d] bf16, shared by all edges of node
  float2 b01 = unpack_bf16(b.x), b23 = unpack_bf16(b.y);
  float2 b45 = unpack_bf16(b.z), b67 = unpack_bf16(b.w);
  float4 w0 = *(const float4*)&W2[8*l];
  float4 w1 = *(const float4*)&W2[8*l + 4];
  float b2v = b2[0];
  int rbase = p0 - node;          // rank base in self-loop-free CSR
  int rounds = (deg2 + 3) >> 2;
  // 2-deep prefetch pipeline
  int e0 = sub;
  bool v0 = e0 < deg2;
  int c0 = __shfl(sreg, v0 ? e0 : 0, 64);
  uint2 A0 = Au2[(size_t)(c0 & NODE_MASK)*16 + l];
  int e1 = 4 + sub;
  bool v1 = e1 < deg2;
  int c1 = c0; uint2 A1 = A0;
  if (rounds > 1){
    if (e1 < 64) c1 = __shfl(sreg, v1 ? e1 : 0, 64);
    else         c1 = csr[p0 + 1 + (v1 ? e1 : 0)];
    A1 = Au2[(size_t)(c1 & NODE_MASK)*16 + l];
  }
  for (int r = 0; r < rounds; ++r){
    int en = 4*(r+2) + sub;
    bool vn = en < deg2;
    int cn = c0; uint2 An = A0;
    if (r + 2 < rounds){
      if (en < 64) cn = __shfl(sreg, vn ? en : 0, 64);
      else         cn = csr[p0 + 1 + (vn ? en : 0)];
      An = Au2[(size_t)(cn & NODE_MASK)*16 + l];
    }
    // compute current edge (c0, A0, v0)
    int g = ((unsigned)c0) >> 27;
    const float* Gp = &G[g*128 + 8*l];
    float4 g0 = *(const float4*)Gp;
    float4 g1 = *(const float4*)(Gp + 4);
    floatx2 a01 = __builtin_amdgcn_cvt_pk_f32_fp8(A0.x, false);
    floatx2 a23 = __builtin_amdgcn_cvt_pk_f32_fp8(A0.x, true);
    floatx2 a45 = __builtin_amdgcn_cvt_pk_f32_fp8(A0.y, false);
    floatx2 a67 = __builtin_amdgcn_cvt_pk_f32_fp8(A0.y, true);
    float part;
    part = fmaxf(a01.x + b01.x + g0.x, 0.f) * w0.x;
    part = fmaf(fmaxf(a01.y + b01.y + g0.y, 0.f), w0.y, part);
    part = fmaf(fmaxf(a23.x + b23.x + g0.z, 0.f), w0.z, part);
    part = fmaf(fmaxf(a23.y + b23.y + g0.w, 0.f), w0.w, part);
    part = fmaf(fmaxf(a45.x + b45.x + g1.x, 0.f), w1.x, part);
    part = fmaf(fmaxf(a45.y + b45.y + g1.y, 0.f), w1.y, part);
    part = fmaf(fmaxf(a67.x + b67.x + g1.z, 0.f), w1.z, part);
    part = fmaf(fmaxf(a67.y + b67.y + g1.w, 0.f), w1.w, part);
#pragma unroll
    for (int mm = 1; mm < 16; mm <<= 1) part += __shfl_xor(part, mm, 64);
    if (l == 0 && v0) tmp[rbase + 4*r + sub] = part + b2v;   // coalesced (CSR order)
    c0 = c1; A0 = A1; v0 = v1;
    c1 = cn; A1 = An; v1 = vn;
  }
}

// ---- out[i] = tmp[epos[i]] : coalesced read of epos + L2-resident gather ----
__global__ void k_remap(const float* __restrict__ tmp, const int* __restrict__ epos,
                        float* __restrict__ out, int e){
  int i = blockIdx.x*blockDim.x + threadIdx.x;
  if (i < e) out[i] = tmp[epos[i]];
}

extern "C" void kernel_launch(void* const* d_in, const int* in_sizes, int n_in,
                              void* d_out, int out_size, void* d_ws, size_t ws_size,
                              hipStream_t stream){
  const float* x     = (const float*)d_in[0];
  const int*   ei    = (const int*)d_in[1];
  const int*   batch = (const int*)d_in[2];
  const int N = in_sizes[2];
  const int E = in_sizes[1] / 2;
  const int* src = ei;
  const int* dst = ei + E;

  unsigned* W = (unsigned*)d_ws;
  const size_t N32 = (size_t)N * 32;
  const size_t N64 = (size_t)N * 64;
  // dword layout: [xl bf16: N32][xr: N64][hE: N64][hD: N64] | ints | gc/G/bsum/tmp
  unsigned short* xlh = (unsigned short*)W;          // N x 64 bf16
  float* xr = (float*)(W + N32);
  float* hE = (float*)(W + N32 + N64);
  float* hD = (float*)(W + N32 + 2*N64);
  // readout aliases (xl/xr/hE dead by then; hD untouched)
  unsigned short* Au16 = (unsigned short*)W;         // N x 128 fp8 (N32 dwords)
  unsigned* Bu = W + N32;                            // N x 64 dwords bf16 (aliases xr)
  int* rowptr = (int*)(W + N32 + 3*N64);             // N+2
  int* cursor = rowptr + (N + 2);                    // N
  int* csr    = cursor + N;                          // N + E
  int* epos   = csr + (N + E);                       // E
  float* gc   = (float*)(epos + E);                  // 8*64
  float* G    = gc + 512;                            // 8*128
  int* bsum   = (int*)(G + 1024);                    // ceil(N/256)
  float* tmp  = (float*)(bsum + 256);                // E floats (CSR-ordered results)

  const int NB = (N + 255) / 256;

  // ---- CSR build (once, reused by all 3 layers + edge MLP) ----
  hipMemsetAsync(cursor, 0, (size_t)N*4, stream);
  k_deg_count<<<(E+255)/256, 256, 0, stream>>>(dst, cursor, E);
  k_scan_a   <<<NB, 256, 0, stream>>>(cursor, rowptr, bsum, N);
  k_scan_b   <<<1, 256, 0, stream>>>(bsum, rowptr, NB, N);
  k_scan_c_selfloop<<<NB, 256, 0, stream>>>(rowptr, bsum, cursor, csr, batch, gc, N);
  k_scatter  <<<(E+255)/256, 256, 0, stream>>>(src, dst, batch, cursor, csr, epos, E);

  // ---- 3 GATv2 layers ----
  const float* h = x;
  float* hn = hD;
  for (int l = 0; l < 3; ++l){
    const float* Wl   = (const float*)d_in[3 + 9*l + 0];
    const float* bl   = (const float*)d_in[3 + 9*l + 1];
    const float* Wr   = (const float*)d_in[3 + 9*l + 2];
    const float* br   = (const float*)d_in[3 + 9*l + 3];
    const float* att  = (const float*)d_in[3 + 9*l + 4];
    const float* Wres = (const float*)d_in[3 + 9*l + 5];
    const float* bias = (const float*)d_in[3 + 9*l + 6];
    const float* lng  = (const float*)d_in[3 + 9*l + 7];
    const float* lnb  = (const float*)d_in[3 + 9*l + 8];
    if (l == 0)
      k_node_transform<32><<<(N+31)/32, 256, 0, stream>>>(h, Wl, bl, Wr, br, Wres, bias, xlh, xr, hn, N);
    else
      k_node_transform<64><<<(N+31)/32, 256, 0, stream>>>(h, Wl, bl, Wr, br, Wres, bias, xlh, xr, hn, N);
    k_gat_edge<<<(N+3)/4, 256, 0, stream>>>((const unsigned*)xlh, xr, att, lng, lnb, rowptr, csr, hn, N);
    h = hn;
    hn = (l == 0) ? hE : hD;   // L0->hD, L1->hE, L2->hD ; final node_repr = hD
  }

  // ---- readout ----
  const float* W1 = (const float*)d_in[30];
  const float* b1 = (const float*)d_in[31];
  const float* W2 = (const float*)d_in[32];
  const float* b2 = (const float*)d_in[33];

  int pool_waves = (N + 63) / 64;
  k_pool      <<<(pool_waves+3)/4, 256, 0, stream>>>(hD, batch, gc, N);
  k_graph_proj<<<1, 1024, 0, stream>>>(gc, W1, b1, G);
  k_node_proj <<<(N+31)/32, 256, 0, stream>>>(hD, W1, Au16, Bu, N);
  k_edge_out_csr<<<(N+3)/4, 256, 0, stream>>>((const uint2*)Au16, (const uint4*)Bu, G,
                                              rowptr, csr, W2, b2, tmp, N);
  k_remap     <<<(E+255)/256, 256, 0, stream>>>(tmp, epos, (float*)d_out, E);
}

// Round 9
// 533.666 us; speedup vs baseline: 1.0866x; 1.0866x over previous
//
#include <hip/hip_runtime.h>
#include <math.h>

typedef float floatx2 __attribute__((ext_vector_type(2)));

#define NODE_MASK 0x07FFFFFF

__device__ __forceinline__ float wave_sum(float v){
#pragma unroll
  for (int m = 1; m < 64; m <<= 1) v += __shfl_xor(v, m, 64);
  return v;
}

__device__ __forceinline__ unsigned pack_bf16(float a, float b){
  unsigned ua = __float_as_uint(a), ub = __float_as_uint(b);
  ua = (ua + 0x7FFFu + ((ua >> 16) & 1u)) >> 16;
  ub = (ub + 0x7FFFu + ((ub >> 16) & 1u)) >> 16;
  return ua | (ub << 16);
}
__device__ __forceinline__ float2 unpack_bf16(unsigned p){
  float2 r;
  r.x = __uint_as_float(p << 16);
  r.y = __uint_as_float(p & 0xFFFF0000u);
  return r;
}

// ---------------- CSR build (dst-major, self-loop first per node) ----------------
// count degrees AND record each edge's arrival rank (coalesced write)
__global__ void k_deg_rank(const int* __restrict__ dst, int* __restrict__ deg,
                           int* __restrict__ rank, int e){
  int i = blockIdx.x*blockDim.x + threadIdx.x;
  if (i < e) rank[i] = atomicAdd(&deg[dst[i]], 1);
}

// ---- parallel exclusive scan of (deg[i]+1) -> rowptr ----
__global__ void k_scan_a(const int* __restrict__ deg, int* __restrict__ rowptr,
                         int* __restrict__ bsum, int n){
  __shared__ int sm[256];
  int i = blockIdx.x*256 + threadIdx.x;
  int v = (i < n) ? (deg[i] + 1) : 0;   // +1 self loop
  sm[threadIdx.x] = v; __syncthreads();
#pragma unroll
  for (int off = 1; off < 256; off <<= 1){
    int t = (threadIdx.x >= off) ? sm[threadIdx.x - off] : 0;
    __syncthreads();
    sm[threadIdx.x] += t;
    __syncthreads();
  }
  if (i < n) rowptr[i] = sm[threadIdx.x] - v;   // exclusive within block
  if (threadIdx.x == 255) bsum[blockIdx.x] = sm[255];
}

__global__ void k_scan_b(int* __restrict__ bsum, int* __restrict__ rowptr, int nb, int n){
  __shared__ int sm[256];
  int t = threadIdx.x;
  int v = (t < nb) ? bsum[t] : 0;
  sm[t] = v; __syncthreads();
#pragma unroll
  for (int off = 1; off < 256; off <<= 1){
    int x = (t >= off) ? sm[t - off] : 0;
    __syncthreads();
    sm[t] += x;
    __syncthreads();
  }
  if (t < nb) bsum[t] = sm[t] - v;              // exclusive block offsets
  if (t == 255) rowptr[n] = sm[255];            // total
}

// fused: add block offset, write self-loop entry (with packed batch), zero gc
__global__ void k_scan_c_selfloop(int* __restrict__ rowptr, const int* __restrict__ bsum,
                                  int* __restrict__ csr,
                                  const int* __restrict__ batch,
                                  float* __restrict__ gc, int n){
  int i = blockIdx.x*256 + threadIdx.x;
  if (i < n){
    int r = rowptr[i] + bsum[blockIdx.x];
    rowptr[i] = r;
    csr[r] = i | (batch[i] << 27);   // self loop entry, batch in top bits
  }
  if (blockIdx.x == 0){
    gc[threadIdx.x] = 0.f;
    gc[threadIdx.x + 256] = 0.f;
  }
}

// atomic-free scatter: 4 edges/thread, independent chains
__global__ void k_scatter(const int* __restrict__ src, const int* __restrict__ dst,
                          const int* __restrict__ batch,
                          const int* __restrict__ rowptr, const int* __restrict__ rank,
                          int* __restrict__ csr, int* __restrict__ epos, int e){
  int i = (blockIdx.x*blockDim.x + threadIdx.x) * 4;
  if (i + 3 < e){
    int4 s4 = *(const int4*)&src[i];
    int4 d4 = *(const int4*)&dst[i];
    int4 r4 = *(const int4*)&rank[i];
    int p0 = rowptr[d4.x] + 1 + r4.x;
    int p1 = rowptr[d4.y] + 1 + r4.y;
    int p2 = rowptr[d4.z] + 1 + r4.z;
    int p3 = rowptr[d4.w] + 1 + r4.w;
    csr[p0] = s4.x | (batch[s4.x] << 27);
    csr[p1] = s4.y | (batch[s4.y] << 27);
    csr[p2] = s4.z | (batch[s4.z] << 27);
    csr[p3] = s4.w | (batch[s4.w] << 27);
    int4 ep; ep.x = p0 - d4.x - 1; ep.y = p1 - d4.y - 1;
    ep.z = p2 - d4.z - 1; ep.w = p3 - d4.w - 1;
    *(int4*)&epos[i] = ep;
  } else {
    for (int j = i; j < e; ++j){
      int d = dst[j], sv = src[j];
      int pos = rowptr[d] + 1 + rank[j];
      csr[pos] = sv | (batch[sv] << 27);
      epos[j] = pos - d - 1;
    }
  }
}

// ------- per-layer node transforms: xl(fp8), xr, residual(+bias); 8 nodes/wave -------
template<int K>
__global__ void k_node_transform(const float* __restrict__ h,
                                 const float* __restrict__ Wl, const float* __restrict__ bl,
                                 const float* __restrict__ Wr, const float* __restrict__ br,
                                 const float* __restrict__ Wres, const float* __restrict__ bias,
                                 unsigned short* __restrict__ xl8, float* __restrict__ xr,
                                 float* __restrict__ res, int n){
  int wq   = (blockIdx.x*blockDim.x + threadIdx.x) >> 6;
  int lane = threadIdx.x & 63;
  int n0 = wq * 8;
  if (n0 >= n) return;
  float hv[8];
#pragma unroll
  for (int j = 0; j < 8; ++j){
    int node = min(n0 + j, n - 1);
    hv[j] = (lane < K) ? h[(size_t)node*K + lane] : 0.f;
  }
  float aL[8], aR[8], aS[8];
  float blv = bl[lane], brv = br[lane], bsv = bias[lane];
#pragma unroll
  for (int j = 0; j < 8; ++j){ aL[j] = blv; aR[j] = brv; aS[j] = bsv; }
#pragma unroll 4
  for (int k = 0; k < K; ++k){
    float wl = Wl[k*64+lane], wr = Wr[k*64+lane], wsv = Wres[k*64+lane];
#pragma unroll
    for (int j = 0; j < 8; ++j){
      float hk = __shfl(hv[j], k, 64);
      aL[j] = fmaf(hk, wl,  aL[j]);
      aR[j] = fmaf(hk, wr,  aR[j]);
      aS[j] = fmaf(hk, wsv, aS[j]);
    }
  }
#pragma unroll
  for (int j = 0; j < 8; ++j){
    int node = n0 + j;
    if (node < n){
      size_t o = (size_t)node*64 + lane;
      float partner = __shfl_xor(aL[j], 1, 64);
      if (!(lane & 1)){
        int pk = __builtin_amdgcn_cvt_pk_fp8_f32(aL[j], partner, 0, false);
        xl8[(size_t)node*32 + (lane >> 1)] = (unsigned short)pk;
      }
      xr[o] = aR[j]; res[o] = aS[j];
    }
  }
}

// --- fused: edge softmax (online, 4 slots, prefetch-2, fp8 xl gathers) + LN + relu ---
__global__ void k_gat_edge(const unsigned* __restrict__ xl_u, const float* __restrict__ xr,
                           const float* __restrict__ att,
                           const float* __restrict__ lng, const float* __restrict__ lnb,
                           const int* __restrict__ rowptr, const int* __restrict__ csr,
                           float* __restrict__ hio /* in: residual, out: h_next */, int n){
  int node = (blockIdx.x*blockDim.x + threadIdx.x) >> 6;
  int lane = threadIdx.x & 63;
  if (node >= n) return;
  int sub = lane >> 4;          // edge slot (0..3)
  int l   = lane & 15;          // channels 4l .. 4l+3
  size_t base = (size_t)node*64 + 4*l;
  float4 xrv  = *(const float4*)&xr[base];
  float4 attv = *(const float4*)&att[4*l];
  int p0 = rowptr[node], p1 = rowptr[node+1];
  int deg = p1 - p0;            // >= 1 (self loop)
  int sreg = csr[p0 + min(lane, deg-1)];   // cache first 64 packed entries in regs
  int rounds = (deg + 3) >> 2;
  float m = -1e30f, dsum = 0.f;
  float a0=0.f, a1=0.f, a2=0.f, a3=0.f;
  // 2-deep prefetch pipeline
  int e0 = sub;
  bool v0 = e0 < deg;
  int s0 = __shfl(sreg, v0 ? e0 : 0, 64) & NODE_MASK;
  unsigned x0 = xl_u[(size_t)s0*16 + l];
  int e1 = 4 + sub;
  bool v1 = e1 < deg;
  unsigned x1 = x0;
  if (rounds > 1){
    int s1;
    if (e1 < 64) s1 = __shfl(sreg, v1 ? e1 : 0, 64);
    else         s1 = csr[p0 + (v1 ? e1 : 0)];
    s1 &= NODE_MASK;
    x1 = xl_u[(size_t)s1*16 + l];
  }
  for (int r = 0; r < rounds; ++r){
    int en = 4*(r+2) + sub;
    bool vn = en < deg;
    unsigned xn = x0;
    if (r + 2 < rounds){
      int sn;
      if (en < 64) sn = __shfl(sreg, vn ? en : 0, 64);
      else         sn = csr[p0 + (vn ? en : 0)];
      sn &= NODE_MASK;
      xn = xl_u[(size_t)sn*16 + l];
    }
    // compute current (x0, v0)
    floatx2 p01 = __builtin_amdgcn_cvt_pk_f32_fp8(x0, false);
    floatx2 p23 = __builtin_amdgcn_cvt_pk_f32_fp8(x0, true);
    float vx = p01.x + xrv.x, vy = p01.y + xrv.y;
    float vz = p23.x + xrv.z, vw = p23.y + xrv.w;
    vx = vx > 0.f ? vx : 0.2f*vx;  vy = vy > 0.f ? vy : 0.2f*vy;
    vz = vz > 0.f ? vz : 0.2f*vz;  vw = vw > 0.f ? vw : 0.2f*vw;
    float partial = fmaf(vx, attv.x, fmaf(vy, attv.y, fmaf(vz, attv.z, vw*attv.w)));
#pragma unroll
    for (int mm = 1; mm < 16; mm <<= 1) partial += __shfl_xor(partial, mm, 64);
    float logit = v0 ? partial : -3e30f;
    float nm = fmaxf(m, logit);
    float sc = __expf(m - nm);
    float w  = __expf(logit - nm);
    dsum = fmaf(dsum, sc, w);
    a0 = fmaf(a0, sc, w*p01.x);
    a1 = fmaf(a1, sc, w*p01.y);
    a2 = fmaf(a2, sc, w*p23.x);
    a3 = fmaf(a3, sc, w*p23.y);
    m = nm;
    x0 = x1; v0 = v1;
    x1 = xn; v1 = vn;
  }
  // merge the 4 sub-groups' online-softmax states (xor 16, then xor 32)
#pragma unroll
  for (int off = 16; off < 64; off <<= 1){
    float mo = __shfl_xor(m, off, 64);
    float M  = fmaxf(m, mo);
    float sc = __expf(m - M);
    dsum *= sc; a0 *= sc; a1 *= sc; a2 *= sc; a3 *= sc;
    m = M;
    dsum += __shfl_xor(dsum, off, 64);
    a0 += __shfl_xor(a0, off, 64);
    a1 += __shfl_xor(a1, off, 64);
    a2 += __shfl_xor(a2, off, 64);
    a3 += __shfl_xor(a3, off, 64);
  }
  float4 resv = *(const float4*)&hio[base];
  float inv = 1.f / dsum;
  float ox = fmaf(a0, inv, resv.x);
  float oy = fmaf(a1, inv, resv.y);
  float oz = fmaf(a2, inv, resv.z);
  float ow = fmaf(a3, inv, resv.w);
  // layernorm over 64 channels; each channel appears 4x across the wave
  float mean = wave_sum(ox + oy + oz + ow) * (1.f/256.f);
  float dx = ox - mean, dy = oy - mean, dz = oz - mean, dw = ow - mean;
  float var = wave_sum(fmaf(dx,dx, fmaf(dy,dy, fmaf(dz,dz, dw*dw)))) * (1.f/256.f);
  float rstd = rsqrtf(var + 1e-5f);
  if (sub == 0){
    float4 lg = *(const float4*)&lng[4*l];
    float4 lb = *(const float4*)&lnb[4*l];
    float4 out;
    out.x = fmaxf(fmaf(dx*rstd, lg.x, lb.x), 0.f);
    out.y = fmaxf(fmaf(dy*rstd, lg.y, lb.y), 0.f);
    out.z = fmaxf(fmaf(dz*rstd, lg.z, lb.z), 0.f);
    out.w = fmaxf(fmaf(dw*rstd, lg.w, lb.w), 0.f);
    *(float4*)&hio[base] = out;
  }
}

// ---------------- global add pool (batch is sorted) ----------------
__global__ void k_pool(const float* __restrict__ h, const int* __restrict__ batch,
                       float* __restrict__ gc, int n){
  int wid  = (blockIdx.x*blockDim.x + threadIdx.x) >> 6;
  int lane = threadIdx.x & 63;
  int n0 = wid*64;
  if (n0 >= n) return;
  int n1 = min(n0+64, n);
  int curg = batch[n0];
  float s = 0.f;
  for (int i = n0; i < n1; ++i){
    int g = batch[i];
    if (g != curg){ atomicAdd(&gc[curg*64+lane], s); s = 0.f; curg = g; }
    s += h[(size_t)i*64 + lane];
  }
  atomicAdd(&gc[curg*64+lane], s);
}

// ---------------- G[g] = gc[g] @ W1c + b1 ----------------
__global__ void k_graph_proj(const float* __restrict__ gc, const float* __restrict__ W1,
                             const float* __restrict__ b1, float* __restrict__ G){
  int g = threadIdx.x >> 7;       // 8 graphs x 128 cols = 1024 threads
  int j = threadIdx.x & 127;
  float a = b1[j];
#pragma unroll 8
  for (int k = 0; k < 64; ++k) a = fmaf(gc[g*64+k], W1[(128+k)*128 + j], a);
  G[g*128 + j] = a;
}

// ---- A = nr @ W1a (fp8 packed) ; B = nr @ W1b (bf16 packed); 8 nodes per wave ----
__global__ void k_node_proj(const float* __restrict__ nr, const float* __restrict__ W1,
                            unsigned short* __restrict__ Au16, unsigned* __restrict__ Bu, int n){
  int wq   = (blockIdx.x*blockDim.x + threadIdx.x) >> 6;
  int lane = threadIdx.x & 63;
  int n0 = wq * 8;
  if (n0 >= n) return;
  float hv[8];
#pragma unroll
  for (int j = 0; j < 8; ++j){
    int node = min(n0 + j, n - 1);
    hv[j] = nr[(size_t)node*64 + lane];
  }
  float a0[8], a1[8], b0[8], b1v[8];
#pragma unroll
  for (int j = 0; j < 8; ++j){ a0[j]=0.f; a1[j]=0.f; b0[j]=0.f; b1v[j]=0.f; }
#pragma unroll 4
  for (int k = 0; k < 64; ++k){
    float2 wa = *(const float2*)&W1[k*128 + 2*lane];
    float2 wb = *(const float2*)&W1[(64+k)*128 + 2*lane];
#pragma unroll
    for (int j = 0; j < 8; ++j){
      float hk = __shfl(hv[j], k, 64);
      a0[j]  = fmaf(hk, wa.x, a0[j]);
      a1[j]  = fmaf(hk, wa.y, a1[j]);
      b0[j]  = fmaf(hk, wb.x, b0[j]);
      b1v[j] = fmaf(hk, wb.y, b1v[j]);
    }
  }
#pragma unroll
  for (int j = 0; j < 8; ++j){
    int node = n0 + j;
    if (node < n){
      size_t o = (size_t)node*64 + lane;
      Au16[o] = (unsigned short)__builtin_amdgcn_cvt_pk_fp8_f32(a0[j], a1[j], 0, false);
      Bu[o] = pack_bf16(b0[j], b1v[j]);
    }
  }
}

// -- final per-edge MLP, dst-major: B[d] once, A[s] fp8-gathered (prefetch-2), tmp coalesced --
// wave per node; 4 edge slots x 16 lanes (8 channels per lane); batch packed in csr
__global__ void k_edge_out_csr(const uint2* __restrict__ Au2, const uint4* __restrict__ Bu4,
                               const float* __restrict__ G,
                               const int* __restrict__ rowptr, const int* __restrict__ csr,
                               const float* __restrict__ W2, const float* __restrict__ b2,
                               float* __restrict__ tmp, int n){
  int node = (blockIdx.x*blockDim.x + threadIdx.x) >> 6;
  int lane = threadIdx.x & 63;
  if (node >= n) return;
  int sub = lane >> 4;
  int l   = lane & 15;            // channels 8l .. 8l+7
  int p0 = rowptr[node];
  int deg2 = rowptr[node+1] - p0 - 1;      // excludes self loop
  if (deg2 <= 0) return;
  int sreg = csr[p0 + 1 + min(lane, deg2-1)];   // cache first 64 packed entries
  uint4 b = Bu4[(size_t)node*16 + l];      // B[d] bf16, shared by all edges of node
  float2 b01 = unpack_bf16(b.x), b23 = unpack_bf16(b.y);
  float2 b45 = unpack_bf16(b.z), b67 = unpack_bf16(b.w);
  float4 w0 = *(const float4*)&W2[8*l];
  float4 w1 = *(const float4*)&W2[8*l + 4];
  float b2v = b2[0];
  int rbase = p0 - node;          // rank base in self-loop-free CSR
  int rounds = (deg2 + 3) >> 2;
  // 2-deep prefetch pipeline
  int e0 = sub;
  bool v0 = e0 < deg2;
  int c0 = __shfl(sreg, v0 ? e0 : 0, 64);
  uint2 A0 = Au2[(size_t)(c0 & NODE_MASK)*16 + l];
  int e1 = 4 + sub;
  bool v1 = e1 < deg2;
  int c1 = c0; uint2 A1 = A0;
  if (rounds > 1){
    if (e1 < 64) c1 = __shfl(sreg, v1 ? e1 : 0, 64);
    else         c1 = csr[p0 + 1 + (v1 ? e1 : 0)];
    A1 = Au2[(size_t)(c1 & NODE_MASK)*16 + l];
  }
  for (int r = 0; r < rounds; ++r){
    int en = 4*(r+2) + sub;
    bool vn = en < deg2;
    int cn = c0; uint2 An = A0;
    if (r + 2 < rounds){
      if (en < 64) cn = __shfl(sreg, vn ? en : 0, 64);
      else         cn = csr[p0 + 1 + (vn ? en : 0)];
      An = Au2[(size_t)(cn & NODE_MASK)*16 + l];
    }
    // compute current edge (c0, A0, v0)
    int g = ((unsigned)c0) >> 27;
    const float* Gp = &G[g*128 + 8*l];
    float4 g0 = *(const float4*)Gp;
    float4 g1 = *(const float4*)(Gp + 4);
    floatx2 a01 = __builtin_amdgcn_cvt_pk_f32_fp8(A0.x, false);
    floatx2 a23 = __builtin_amdgcn_cvt_pk_f32_fp8(A0.x, true);
    floatx2 a45 = __builtin_amdgcn_cvt_pk_f32_fp8(A0.y, false);
    floatx2 a67 = __builtin_amdgcn_cvt_pk_f32_fp8(A0.y, true);
    float part;
    part = fmaxf(a01.x + b01.x + g0.x, 0.f) * w0.x;
    part = fmaf(fmaxf(a01.y + b01.y + g0.y, 0.f), w0.y, part);
    part = fmaf(fmaxf(a23.x + b23.x + g0.z, 0.f), w0.z, part);
    part = fmaf(fmaxf(a23.y + b23.y + g0.w, 0.f), w0.w, part);
    part = fmaf(fmaxf(a45.x + b45.x + g1.x, 0.f), w1.x, part);
    part = fmaf(fmaxf(a45.y + b45.y + g1.y, 0.f), w1.y, part);
    part = fmaf(fmaxf(a67.x + b67.x + g1.z, 0.f), w1.z, part);
    part = fmaf(fmaxf(a67.y + b67.y + g1.w, 0.f), w1.w, part);
#pragma unroll
    for (int mm = 1; mm < 16; mm <<= 1) part += __shfl_xor(part, mm, 64);
    if (l == 0 && v0) tmp[rbase + 4*r + sub] = part + b2v;   // coalesced (CSR order)
    c0 = c1; A0 = A1; v0 = v1;
    c1 = cn; A1 = An; v1 = vn;
  }
}

// ---- out[i] = tmp[epos[i]] : coalesced read of epos + L2-resident gather ----
__global__ void k_remap(const float* __restrict__ tmp, const int* __restrict__ epos,
                        float* __restrict__ out, int e){
  int i = blockIdx.x*blockDim.x + threadIdx.x;
  if (i < e) out[i] = tmp[epos[i]];
}

extern "C" void kernel_launch(void* const* d_in, const int* in_sizes, int n_in,
                              void* d_out, int out_size, void* d_ws, size_t ws_size,
                              hipStream_t stream){
  const float* x     = (const float*)d_in[0];
  const int*   ei    = (const int*)d_in[1];
  const int*   batch = (const int*)d_in[2];
  const int N = in_sizes[2];
  const int E = in_sizes[1] / 2;
  const int* src = ei;
  const int* dst = ei + E;

  unsigned* W = (unsigned*)d_ws;
  const size_t N16 = (size_t)N * 16;
  const size_t N32 = (size_t)N * 32;
  const size_t N64 = (size_t)N * 64;
  // dword layout: [xl fp8: N16][xr: N64][hE: N64][hD: N64] | ints | gc/G/bsum/tmp
  unsigned short* xl8 = (unsigned short*)W;          // N x 64 fp8 (as ushort pairs)
  float* xr = (float*)(W + N16);
  float* hE = (float*)(W + N16 + N64);
  float* hD = (float*)(W + N16 + 2*N64);
  // readout aliases (xl/xr/hE dead by then; hD untouched)
  unsigned short* Au16 = (unsigned short*)W;         // N x 64 ushorts (N32 dwords)
  unsigned* Bu = W + N32;                            // N x 64 dwords bf16 (ends < hD)
  int* rowptr = (int*)(W + N16 + 3*N64);             // N+2
  int* deg    = rowptr + (N + 2);                    // N
  int* csr    = deg + N;                             // N + E
  int* epos   = csr + (N + E);                       // E
  int* rank   = epos + E;                            // E
  float* gc   = (float*)(rank + E);                  // 8*64
  float* G    = gc + 512;                            // 8*128
  int* bsum   = (int*)(G + 1024);                    // ceil(N/256)
  float* tmp  = (float*)(bsum + 256);                // E floats (CSR-ordered results)

  const int NB = (N + 255) / 256;

  // ---- CSR build (once, reused by all 3 layers + edge MLP) ----
  hipMemsetAsync(deg, 0, (size_t)N*4, stream);
  k_deg_rank <<<(E+255)/256, 256, 0, stream>>>(dst, deg, rank, E);
  k_scan_a   <<<NB, 256, 0, stream>>>(deg, rowptr, bsum, N);
  k_scan_b   <<<1, 256, 0, stream>>>(bsum, rowptr, NB, N);
  k_scan_c_selfloop<<<NB, 256, 0, stream>>>(rowptr, bsum, csr, batch, gc, N);
  k_scatter  <<<(E/4+255)/256, 256, 0, stream>>>(src, dst, batch, rowptr, rank, csr, epos, E);

  // ---- 3 GATv2 layers ----
  const float* h = x;
  float* hn = hD;
  for (int l = 0; l < 3; ++l){
    const float* Wl   = (const float*)d_in[3 + 9*l + 0];
    const float* bl   = (const float*)d_in[3 + 9*l + 1];
    const float* Wr   = (const float*)d_in[3 + 9*l + 2];
    const float* br   = (const float*)d_in[3 + 9*l + 3];
    const float* att  = (const float*)d_in[3 + 9*l + 4];
    const float* Wres = (const float*)d_in[3 + 9*l + 5];
    const float* bias = (const float*)d_in[3 + 9*l + 6];
    const float* lng  = (const float*)d_in[3 + 9*l + 7];
    const float* lnb  = (const float*)d_in[3 + 9*l + 8];
    if (l == 0)
      k_node_transform<32><<<(N+31)/32, 256, 0, stream>>>(h, Wl, bl, Wr, br, Wres, bias, xl8, xr, hn, N);
    else
      k_node_transform<64><<<(N+31)/32, 256, 0, stream>>>(h, Wl, bl, Wr, br, Wres, bias, xl8, xr, hn, N);
    k_gat_edge<<<(N+3)/4, 256, 0, stream>>>((const unsigned*)xl8, xr, att, lng, lnb, rowptr, csr, hn, N);
    h = hn;
    hn = (l == 0) ? hE : hD;   // L0->hD, L1->hE, L2->hD ; final node_repr = hD
  }

  // ---- readout ----
  const float* W1 = (const float*)d_in[30];
  const float* b1 = (const float*)d_in[31];
  const float* W2 = (const float*)d_in[32];
  const float* b2 = (const float*)d_in[33];

  int pool_waves = (N + 63) / 64;
  k_pool      <<<(pool_waves+3)/4, 256, 0, stream>>>(hD, batch, gc, N);
  k_graph_proj<<<1, 1024, 0, stream>>>(gc, W1, b1, G);
  k_node_proj <<<(N+31)/32, 256, 0, stream>>>(hD, W1, Au16, Bu, N);
  k_edge_out_csr<<<(N+3)/4, 256, 0, stream>>>((const uint2*)Au16, (const uint4*)Bu, G,
                                              rowptr, csr, W2, b2, tmp, N);
  k_remap     <<<(E+255)/256, 256, 0, stream>>>(tmp, epos, (float*)d_out, E);
}